// Round 1
// baseline (1363.536 us; speedup 1.0000x reference)
//
#include <hip/hip_runtime.h>

typedef __bf16 v8bf __attribute__((ext_vector_type(8)));
typedef float v4f __attribute__((ext_vector_type(4)));
typedef unsigned short u16;
typedef unsigned int u32;

#define DEVI __device__ __forceinline__

constexpr int LX = 168, FF = 64;
constexpr int LY = 72, FT = 22, FOUTC = 10;
constexpr int HID = 256;
constexpr int HSTR = 264;   // u16/row for 16x256 tiles (528B = 33*16)
constexpr int UST2 = 40;
constexpr int SSTR = 264;   // slab row stride (r-gate Whh rows 0..255)
constexpr int XSTR = 72;    // x stage row stride (144B, 16B aligned, banks spread)

// bf16 weight cache layout in d_ws (u16 element offsets; all 16B-aligned)
constexpr int W_EWIH = 0;                      // 768*64
constexpr int W_EWHH = 49152;                  // 768*256
constexpr int W_DWIH = 245760;                 // 768*32
constexpr int W_DWHH = 270336;                 // 768*256
constexpr int W_THW0 = 466944;                 // 128*256
constexpr int W_THW1 = 499712;                 // 2*128
constexpr int W_CLW0 = 499968;                 // 128*256
constexpr int W_CLW1 = 532736;                 // 8*128
constexpr int W_TOTAL = 533760;

DEVI u16 f2bf(float f) {
  u32 x; __builtin_memcpy(&x, &f, 4);
  return (u16)((x + 0x7FFFu + ((x >> 16) & 1u)) >> 16);  // RNE (h feeds recurrence)
}
DEVI float sigm(float x) { return __builtin_amdgcn_rcpf(1.f + __expf(-x)); }
DEVI float tanh_(float x) {
  float e = __expf(-2.f * fabsf(x));
  return copysignf((1.f - e) * __builtin_amdgcn_rcpf(1.f + e), x);
}
DEVI float smelu_(float x) {
  if (x >= 1.1f) return x;
  if (x <= -1.1f) return 0.f;
  float u = x + 1.1f;
  return u * u * (1.f / 4.4f);
}
DEVI v8bf ld8(const u16* p) { return *reinterpret_cast<const v8bf*>(p); }
DEVI v4f ldw(const u16* p) { return *reinterpret_cast<const v4f*>(p); }
DEVI v8bf asbf(v4f x) { return __builtin_bit_cast(v8bf, x); }
DEVI void pin(v4f& x) { asm("" : "+v"(x)); }       // defeat rematerialization
DEVI v4f mfma16(v8bf a, v8bf b, v4f c) {
  return __builtin_amdgcn_mfma_f32_16x16x32_bf16(a, b, c, 0, 0, 0);
}

// ---- prologue: convert all weight matrices f32 -> bf16 into d_ws ----
__global__ void cvt_weights(const float* __restrict__ eWih, const float* __restrict__ eWhh,
                            const float* __restrict__ dWih, const float* __restrict__ dWhh,
                            const float* __restrict__ thW0, const float* __restrict__ thW1,
                            const float* __restrict__ clW0, const float* __restrict__ clW1,
                            u16* __restrict__ ws) {
  const int i = blockIdx.x * 256 + threadIdx.x;
  if (i >= W_TOTAL) return;
  const float* src; int off;
  if      (i < W_EWHH) { src = eWih; off = W_EWIH; }
  else if (i < W_DWIH) { src = eWhh; off = W_EWHH; }
  else if (i < W_DWHH) { src = dWih; off = W_DWIH; }
  else if (i < W_THW0) { src = dWhh; off = W_DWHH; }
  else if (i < W_THW1) { src = thW0; off = W_THW0; }
  else if (i < W_CLW0) { src = thW1; off = W_THW1; }
  else if (i < W_CLW1) { src = clW0; off = W_CLW0; }
  else                 { src = clW1; off = W_CLW1; }
  ws[i] = f2bf(src[i - off]);
}

// 1024 threads = 16 waves; wave w owns ONE gate col-tile c = w.
// Occupancy play: per-wave persistent weights halve (z,n B-frags = 64 regs),
// h read on-the-fly in the k-loop (no a[8]), x staged through LDS one step
// ahead -> fits the 128-reg/wave cap -> 4 waves/SIMD instead of 2.
// Encoder: h double-buffered, 1 barrier/step. Decoder: h double-buffered,
// a1 SINGLE-buffered in aux; GEMM2(t-2) reads aux before bar1, GEMM1(t-1)
// writes aux between bar1 and bar2. aux doubles as the encoder x-stage
// buffer (encoder-only vs decoder-only use).
__global__ __launch_bounds__(1024, 4) void encdec_kernel(
    const float* __restrict__ xf, const float* __restrict__ yt, const float* __restrict__ pp,
    const float* __restrict__ ebih, const float* __restrict__ ebhh,
    const float* __restrict__ dbih, const float* __restrict__ dbhh,
    const float* __restrict__ thb0, const float* __restrict__ thb1,
    const float* __restrict__ clb0, const float* __restrict__ clb1,
    const u16* __restrict__ ws, float* __restrict__ outp) {
  __shared__ __align__(16) u16 slab[256 * SSTR];   // r-gate Whh rows (132 KB)
  __shared__ __align__(16) u16 hls[2][16 * HSTR];  // h double buffer (enc+dec)
  __shared__ __align__(16) u16 aux[16 * HSTR];     // enc: x dbuf [2][16*XSTR]; dec: a1
  __shared__ __align__(16) u16 uls[2][16 * UST2];

  const u16* eWih = ws + W_EWIH;
  const u16* eWhh = ws + W_EWHH;
  const u16* dWih = ws + W_DWIH;
  const u16* dWhh = ws + W_DWHH;
  const u16* thW0 = ws + W_THW0;
  const u16* thW1 = ws + W_THW1;
  const u16* clW0 = ws + W_CLW0;
  const u16* clW1 = ws + W_CLW1;

  const int tid = threadIdx.x;
  const int wave = tid >> 6;        // 16 waves
  const int lane = tid & 63;
  const int col16 = lane & 15;
  const int quad = lane >> 4;
  const int n0 = blockIdx.x * 16;

  const int cidx = wave * 16 + col16;          // owned gate/output column
  const int mr = cidx, mz = 256 + cidx, mn = 512 + cidx;

  float hreg[4] = {0.f, 0.f, 0.f, 0.f};

  // Persistent z,n Whh B-fragments (64 regs; allocator may park in AGPR).
  v4f wz[8], wn[8];
  float bsr, bsz, bin_, bhn;

  // x staging: 1 element per thread (16 rows x 64 cols = 1024)
  const int xk = lane;                          // col within FF
  const float* xsrc = xf + ((size_t)(n0 + wave) * LX) * FF + xk;

  // ================= encoder phase =================
  {
    for (int i = tid; i < 256 * 32; i += 1024) {  // stage r-gate Whh slab
      const int row = i >> 5, kb = (i & 31) << 3;
      *reinterpret_cast<v8bf*>(&slab[row * SSTR + kb]) = ld8(eWhh + row * HID + kb);
    }
    for (int i = tid; i < 16 * HSTR; i += 1024) hls[0][i] = 0;
    aux[wave * XSTR + xk] = f2bf(xsrc[0]);        // stage x(0) into xls[0]
#pragma unroll
    for (int k = 0; k < 8; ++k) {
      wz[k] = ldw(eWhh + (size_t)mz * HID + k * 32 + quad * 8); pin(wz[k]);
      wn[k] = ldw(eWhh + (size_t)mn * HID + k * 32 + quad * 8); pin(wn[k]);
    }
    bsr = ebih[mr] + ebhh[mr];
    bsz = ebih[mz] + ebhh[mz];
    bin_ = ebih[mn];
    bhn = ebhh[mn];

    const u16* sp  = slab + cidx * SSTR + quad * 8;
    const u16* pwr = eWih + (size_t)mr * FF + quad * 8;
    const u16* pwz = eWih + (size_t)mz * FF + quad * 8;
    const u16* pwn = eWih + (size_t)mn * FF + quad * 8;
    __syncthreads();  // slab + h-init + x(0) visible

#pragma unroll 1
    for (int t = 0; t < LX; ++t) {
      float xnext = 0.f;
      if (t + 1 < LX) xnext = xsrc[(size_t)(t + 1) * FF];  // issue early, use late

      const u16* hb = hls[t & 1] + col16 * HSTR + quad * 8;
      v4f az = {bsz, bsz, bsz, bsz};
      v4f ar = {bsr, bsr, bsr, bsr};
      v4f an = {bhn, bhn, bhn, bhn};
      v4f ai = {bin_, bin_, bin_, bin_};
#pragma unroll
      for (int k = 0; k < 8; ++k) {            // on-the-fly h fragments
        const v8bf a = ld8(hb + k * 32);
        az = mfma16(a, asbf(wz[k]), az);
        ar = mfma16(a, ld8(sp + k * 32), ar);
        an = mfma16(a, asbf(wn[k]), an);
      }
      const u16* xb = aux + (t & 1) * (16 * XSTR) + col16 * XSTR + quad * 8;
      const v8bf xa0 = ld8(xb);
      const v8bf xa1 = ld8(xb + 32);
      az = mfma16(xa0, ld8(pwz), az);
      az = mfma16(xa1, ld8(pwz + 32), az);
      ar = mfma16(xa0, ld8(pwr), ar);
      ar = mfma16(xa1, ld8(pwr + 32), ar);
      ai = mfma16(xa0, ld8(pwn), ai);
      ai = mfma16(xa1, ld8(pwn + 32), ai);
#pragma unroll
      for (int r = 0; r < 4; ++r) {
        const float zg = sigm(az[r]);
        const float rg = sigm(ar[r]);
        const float ng = tanh_(ai[r] + rg * an[r]);
        hreg[r] = (1.f - zg) * ng + zg * hreg[r];
        hls[(t + 1) & 1][(quad * 4 + r) * HSTR + cidx] = f2bf(hreg[r]);
      }
      if (t + 1 < LX)
        aux[((t + 1) & 1) * (16 * XSTR) + wave * XSTR + xk] = f2bf(xnext);
      __syncthreads();
    }
  }
  // h_enc = H(168) in hls[0]  (LX even)

  // ================= decoder phase =================
  {
    for (int i = tid; i < 256 * 32; i += 1024) {  // restage slab with dWhh r rows
      const int row = i >> 5, kb = (i & 31) << 3;
      *reinterpret_cast<v8bf*>(&slab[row * SSTR + kb]) = ld8(dWhh + row * HID + kb);
    }
#pragma unroll
    for (int k = 0; k < 8; ++k) {
      wz[k] = ldw(dWhh + (size_t)mz * HID + k * 32 + quad * 8); pin(wz[k]);
      wn[k] = ldw(dWhh + (size_t)mn * HID + k * 32 + quad * 8); pin(wn[k]);
    }
    bsr = dbih[mr] + dbhh[mr];
    bsz = dbih[mz] + dbhh[mz];
    bin_ = dbih[mn];
    bhn = dbhh[mn];

    const bool isTh = (wave < 8);
    const int wrow = (wave & 7) * 16 + col16;        // head W0 row
    const u16* pW0 = (isTh ? thW0 : clW0) + (size_t)wrow * HID + quad * 8;
    const float hb0 = isTh ? thb0[wrow] : clb0[wrow];

    const bool w1th = (col16 < 2);
    const bool w1cl = (col16 >= 2 && col16 < FOUTC);
    const float b1v = w1th ? thb1[col16] : (w1cl ? clb1[col16 - 2] : 0.f);

    const u16* sp  = slab + cidx * SSTR + quad * 8;
    const u16* pur = dWih + (size_t)mr * 32 + quad * 8;
    const u16* puz = dWih + (size_t)mz * 32 + quad * 8;
    const u16* pun = dWih + (size_t)mn * 32 + quad * 8;

    const int srr = tid >> 5, scc = tid & 31;        // u staging (tid < 512)
    const size_t ybase = (size_t)(n0 + srr) * (LY + 1);
    if (tid < 512) {
      const float v = (scc < FT) ? yt[ybase * FT + scc] : pp[ybase * FOUTC + (scc - FT)];
      uls[0][srr * UST2 + scc] = f2bf(v);
    }

    // GEMM2 for step s: out(s) = a1(s) @ W1^T + b1, a1(s) read from aux.
    auto gemm2 = [&](int s) {
      const u16* arow = aux + col16 * HSTR + quad * 8;
      v4f acc = {0.f, 0.f, 0.f, 0.f};
#pragma unroll
      for (int kt = 0; kt < 8; ++kt) {
        v8bf b;
#pragma unroll
        for (int j = 0; j < 8; ++j) b[j] = (__bf16)0.0f;
        if (kt < 4) { if (w1th) b = ld8(thW1 + col16 * 128 + kt * 32 + quad * 8); }
        else        { if (w1cl) b = ld8(clW1 + (col16 - 2) * 128 + (kt - 4) * 32 + quad * 8); }
        acc = mfma16(ld8(arow + kt * 32), b, acc);
      }
      if (col16 < FOUTC) {
#pragma unroll
        for (int r = 0; r < 4; ++r)
          outp[((size_t)(n0 + quad * 4 + r) * LY + s) * FOUTC + col16] = acc[r] + b1v;
      }
    };

    // GEMM1 for step s: a1(s) = smelu(H(s+1) @ W0^T + b0), A re-read from hpar.
    auto gemm1 = [&](const u16* hbase) {
      const u16* hA = hbase + col16 * HSTR + quad * 8;
      v4f acc = {0.f, 0.f, 0.f, 0.f};
#pragma unroll
      for (int k = 0; k < 8; ++k)
        acc = mfma16(ld8(hA + k * 32), ld8(pW0 + k * 32), acc);
#pragma unroll
      for (int r = 0; r < 4; ++r)
        aux[(quad * 4 + r) * HSTR + cidx] = f2bf(smelu_(acc[r] + hb0));
    };

    __syncthreads();  // slab + u_0 visible (last enc h write fenced by enc barrier)

#pragma unroll 1
    for (int t = 0; t < LY; ++t) {
      float un = 0.f;
      if (tid < 512 && t + 1 < LY)
        un = (scc < FT) ? yt[(ybase + t) * FT + scc]
                        : pp[(ybase + t) * FOUTC + (scc - FT)];

      // ---- phase A ----
      if (wave == 0 && t >= 2) gemm2(t - 2);     // reads aux (written step t-1 phase B)

      const v8bf ua = ld8(uls[t & 1] + col16 * UST2 + quad * 8);
      const u16* hb = hls[t & 1] + col16 * HSTR + quad * 8;
      v4f az = {bsz, bsz, bsz, bsz};
      v4f ar = {bsr, bsr, bsr, bsr};
      v4f an = {bhn, bhn, bhn, bhn};
      v4f ai = {bin_, bin_, bin_, bin_};
#pragma unroll
      for (int k = 0; k < 8; ++k) {
        const v8bf a = ld8(hb + k * 32);
        az = mfma16(a, asbf(wz[k]), az);
        ar = mfma16(a, ld8(sp + k * 32), ar);
        an = mfma16(a, asbf(wn[k]), an);
      }
      az = mfma16(ua, ld8(puz), az);
      ar = mfma16(ua, ld8(pur), ar);
      ai = mfma16(ua, ld8(pun), ai);
#pragma unroll
      for (int r = 0; r < 4; ++r) {
        const float zg = sigm(az[r]);
        const float rg = sigm(ar[r]);
        const float ng = tanh_(ai[r] + rg * an[r]);
        hreg[r] = (1.f - zg) * ng + zg * hreg[r];
        hls[(t + 1) & 1][(quad * 4 + r) * HSTR + cidx] = f2bf(hreg[r]);
      }
      if (tid < 512 && t + 1 < LY) uls[(t + 1) & 1][srr * UST2 + scc] = f2bf(un);
      __syncthreads();  // bar1: aux reads (GEMM2) done; H(t+1)/u(t+1) visible

      // ---- phase B ----
      if (t >= 1) gemm1(hls[t & 1]);             // a1(t-1) from H(t); writes aux
      __syncthreads();  // bar2: aux(t-1) visible for next step's GEMM2
    }

    // ---- epilogue: GEMM2(LY-2), then GEMM1(LY-1), then GEMM2(LY-1) ----
    if (wave == 0) gemm2(LY - 2);                // aux holds a1(LY-2)
    __syncthreads();
    gemm1(hls[LY & 1]);                          // a1(LY-1) from H(LY) (= hls[0])
    __syncthreads();
    if (wave == 0) gemm2(LY - 1);
  }
}

extern "C" void kernel_launch(void* const* d_in, const int* in_sizes, int n_in,
                              void* d_out, int out_size, void* d_ws, size_t ws_size,
                              hipStream_t stream) {
  (void)in_sizes; (void)n_in; (void)ws_size; (void)out_size;
  const float* xf   = (const float*)d_in[0];
  // d_in[1] = x : unused by forward
  const float* yt   = (const float*)d_in[2];
  const float* pp   = (const float*)d_in[3];
  const float* eWih = (const float*)d_in[4];
  const float* eWhh = (const float*)d_in[5];
  const float* ebih = (const float*)d_in[6];
  const float* ebhh = (const float*)d_in[7];
  const float* dWih = (const float*)d_in[8];
  const float* dWhh = (const float*)d_in[9];
  const float* dbih = (const float*)d_in[10];
  const float* dbhh = (const float*)d_in[11];
  const float* thW0 = (const float*)d_in[12];
  const float* thb0 = (const float*)d_in[13];
  const float* thW1 = (const float*)d_in[14];
  const float* thb1 = (const float*)d_in[15];
  const float* clW0 = (const float*)d_in[16];
  const float* clb0 = (const float*)d_in[17];
  const float* clW1 = (const float*)d_in[18];
  const float* clb1 = (const float*)d_in[19];
  float* outp = (float*)d_out;
  u16* ws = (u16*)d_ws;  // needs W_TOTAL*2 ~= 1.04 MB of scratch

  cvt_weights<<<dim3((W_TOTAL + 255) / 256), dim3(256), 0, stream>>>(
      eWih, eWhh, dWih, dWhh, thW0, thW1, clW0, clW1, ws);
  encdec_kernel<<<dim3(128), dim3(1024), 0, stream>>>(
      xf, yt, pp, ebih, ebhh, dbih, dbhh, thb0, thb1, clb0, clb1, ws, outp);
}

// Round 2
// 1344.022 us; speedup vs baseline: 1.0145x; 1.0145x over previous
//
#include <hip/hip_runtime.h>

typedef __bf16 v8bf __attribute__((ext_vector_type(8)));
typedef float v4f __attribute__((ext_vector_type(4)));
typedef float v4ff __attribute__((ext_vector_type(4)));
typedef unsigned short u16;
typedef unsigned int u32;

#define DEVI __device__ __forceinline__

constexpr int LX = 168, FF = 64;
constexpr int LY = 72, FT = 22, FOUTC = 10;
constexpr int HID = 256;
constexpr int HSTR = 264;   // u16/row for 16x256 tiles (528B = 33*16)
constexpr int UST2 = 40;
constexpr int SSTR = 264;   // slab row stride (r-gate Whh rows 0..255)

// bf16 weight cache layout in d_ws (u16 element offsets; all 16B-aligned)
constexpr int W_EWIH = 0;                      // 768*64
constexpr int W_EWHH = 49152;                  // 768*256
constexpr int W_DWIH = 245760;                 // 768*32
constexpr int W_DWHH = 270336;                 // 768*256
constexpr int W_THW0 = 466944;                 // 128*256
constexpr int W_THW1 = 499712;                 // 2*128
constexpr int W_CLW0 = 499968;                 // 128*256
constexpr int W_CLW1 = 532736;                 // 8*128
constexpr int W_TOTAL = 533760;

DEVI u16 f2bf(float f) {
  u32 x; __builtin_memcpy(&x, &f, 4);
  return (u16)((x + 0x7FFFu + ((x >> 16) & 1u)) >> 16);  // RNE (h feeds recurrence)
}
DEVI float sigm(float x) { return __builtin_amdgcn_rcpf(1.f + __expf(-x)); }
DEVI float tanh_(float x) {
  float e = __expf(-2.f * fabsf(x));
  return copysignf((1.f - e) * __builtin_amdgcn_rcpf(1.f + e), x);
}
DEVI float smelu_(float x) {
  if (x >= 1.1f) return x;
  if (x <= -1.1f) return 0.f;
  float u = x + 1.1f;
  return u * u * (1.f / 4.4f);
}
DEVI v8bf ld8(const u16* p) { return *reinterpret_cast<const v8bf*>(p); }
DEVI v4f ldw(const u16* p) { return *reinterpret_cast<const v4f*>(p); }
DEVI v8bf asbf(v4f x) { return __builtin_bit_cast(v8bf, x); }
DEVI void pin(v4f& x) { asm("" : "+v"(x)); }       // defeat rematerialization
DEVI v4f mfma16(v8bf a, v8bf b, v4f c) {
  return __builtin_amdgcn_mfma_f32_16x16x32_bf16(a, b, c, 0, 0, 0);
}
DEVI v8bf cvt2f(v4ff lo, v4ff hi) {
  v8bf r;
#pragma unroll
  for (int j = 0; j < 4; ++j) { r[j] = (__bf16)lo[j]; r[4 + j] = (__bf16)hi[j]; }
  return r;
}

// ---- prologue: convert all weight matrices f32 -> bf16 into d_ws ----
__global__ void cvt_weights(const float* __restrict__ eWih, const float* __restrict__ eWhh,
                            const float* __restrict__ dWih, const float* __restrict__ dWhh,
                            const float* __restrict__ thW0, const float* __restrict__ thW1,
                            const float* __restrict__ clW0, const float* __restrict__ clW1,
                            u16* __restrict__ ws) {
  const int i = blockIdx.x * 256 + threadIdx.x;
  if (i >= W_TOTAL) return;
  const float* src; int off;
  if      (i < W_EWHH) { src = eWih; off = W_EWIH; }
  else if (i < W_DWIH) { src = eWhh; off = W_EWHH; }
  else if (i < W_DWHH) { src = dWih; off = W_DWIH; }
  else if (i < W_THW0) { src = dWhh; off = W_DWHH; }
  else if (i < W_THW1) { src = thW0; off = W_THW0; }
  else if (i < W_CLW0) { src = thW1; off = W_THW1; }
  else if (i < W_CLW1) { src = clW0; off = W_CLW0; }
  else                 { src = clW1; off = W_CLW1; }
  ws[i] = f2bf(src[i - off]);
}

// 512 threads = 8 waves; wave w owns gate col-tiles c = w, w+8 (round-0
// structure: 2 waves/SIMD, 128 arch + 128 pinned AGPR = the 256/wave cap).
// Round-2 edits: (1) x(t+1) loaded mid-step, cvt'd to bf16 PRE-barrier so
// post-barrier x-MFMAs are register-ready (no vmcnt/cvt on critical path);
// (2) encoder h-frags stream with 2-ahead rotation (-24 regs, pays for the
// xa carry); (3) biases folded into MFMA C-init (kills ~24 VALU/thread/step
// in the serial pointwise tail); (4) s_setprio around MFMA chains.
// Decoder keeps a[8] preload: gemm1 NEEDS the register copy of h_t because
// hls[0] is single-buffered and overwritten before gemm1 runs.
__global__ __launch_bounds__(512, 2) void encdec_kernel(
    const float* __restrict__ xf, const float* __restrict__ yt, const float* __restrict__ pp,
    const float* __restrict__ ebih, const float* __restrict__ ebhh,
    const float* __restrict__ dbih, const float* __restrict__ dbhh,
    const float* __restrict__ thb0, const float* __restrict__ thb1,
    const float* __restrict__ clb0, const float* __restrict__ clb1,
    const u16* __restrict__ ws, float* __restrict__ outp) {
  __shared__ __align__(16) u16 slab[256 * SSTR];   // r-gate Whh rows (132 KB)
  __shared__ __align__(16) u16 hls[2][16 * HSTR];  // enc: h dbuf; dec: h=hls[0], a1#0=hls[1]
  __shared__ __align__(16) u16 a1x[16 * HSTR];     // a1 buffer #1
  __shared__ __align__(16) u16 uls[2][16 * UST2];

  const u16* eWih = ws + W_EWIH;
  const u16* eWhh = ws + W_EWHH;
  const u16* dWih = ws + W_DWIH;
  const u16* dWhh = ws + W_DWHH;
  const u16* thW0 = ws + W_THW0;
  const u16* thW1 = ws + W_THW1;
  const u16* clW0 = ws + W_CLW0;
  const u16* clW1 = ws + W_CLW1;

  const int tid = threadIdx.x;
  const int wave = tid >> 6;        // 8 waves
  const int lane = tid & 63;
  const int col16 = lane & 15;
  const int quad = lane >> 4;
  const int n0 = blockIdx.x * 16;

  for (int i = tid; i < 16 * HSTR; i += 512) hls[0][i] = 0;

  float hreg[2][4];
#pragma unroll
  for (int j = 0; j < 2; ++j)
#pragma unroll
    for (int r = 0; r < 4; ++r) hreg[j][r] = 0.f;

  // Persistent (laundered -> AGPR): z,n Whh fragments (128 regs).
  v4f wz[2][8], wn[2][8];
  float bsr[2], bsz[2], bin_[2], bhn[2];

  // ================= encoder phase =================
  {
    for (int i = tid; i < 256 * 32; i += 512) {  // stage r-gate Whh slab
      const int row = i >> 5, kb = (i & 31) << 3;
      *reinterpret_cast<v8bf*>(&slab[row * SSTR + kb]) = ld8(eWhh + row * HID + kb);
    }
#pragma unroll
    for (int j = 0; j < 2; ++j) {
      const int c = wave + 8 * j;
      const int mr = c * 16 + col16, mz = 256 + mr, mn = 512 + mr;
#pragma unroll
      for (int k = 0; k < 8; ++k) {
        wz[j][k] = ldw(eWhh + (size_t)mz * HID + k * 32 + quad * 8); pin(wz[j][k]);
        wn[j][k] = ldw(eWhh + (size_t)mn * HID + k * 32 + quad * 8); pin(wn[j][k]);
      }
      bsr[j] = ebih[mr] + ebhh[mr];
      bsz[j] = ebih[mz] + ebhh[mz];
      bin_[j] = ebih[mn];
      bhn[j] = ebhh[mn];
    }
    const float* xbase = xf + (size_t)(n0 + col16) * LX * FF + quad * 8;
    const u16* sp0 = slab + (wave * 16 + col16) * SSTR + quad * 8;
    const u16* sp1 = slab + ((wave + 8) * 16 + col16) * SSTR + quad * 8;

    // x(0) fragments pre-cvt'd before the loop
    v8bf xa0, xa1;
    {
      const v4ff x0 = *(const v4ff*)(xbase);
      const v4ff x1 = *(const v4ff*)(xbase + 4);
      const v4ff x2 = *(const v4ff*)(xbase + 32);
      const v4ff x3 = *(const v4ff*)(xbase + 36);
      xa0 = cvt2f(x0, x1);
      xa1 = cvt2f(x2, x3);
    }
    __syncthreads();  // slab + h-init visible

#pragma unroll 1
    for (int t = 0; t < LX; ++t) {
      const u16* hb = hls[t & 1] + col16 * HSTR + quad * 8;

      // bias-folded accumulator init
      v4f az[2], ar[2], an[2], ai[2];
#pragma unroll
      for (int j = 0; j < 2; ++j) {
        az[j] = (v4f){bsz[j], bsz[j], bsz[j], bsz[j]};
        ar[j] = (v4f){bsr[j], bsr[j], bsr[j], bsr[j]};
        an[j] = (v4f){bhn[j], bhn[j], bhn[j], bhn[j]};
        ai[j] = (v4f){bin_[j], bin_[j], bin_[j], bin_[j]};
      }

      __builtin_amdgcn_s_setprio(1);
      // 6 independent h-chains, k-outer interleave; h-frags stream 2-ahead
      v8bf ak = ld8(hb), ak1 = ld8(hb + 32);
#pragma unroll
      for (int k = 0; k < 8; ++k) {
        az[0] = mfma16(ak, asbf(wz[0][k]), az[0]);
        az[1] = mfma16(ak, asbf(wz[1][k]), az[1]);
        ar[0] = mfma16(ak, ld8(sp0 + k * 32), ar[0]);
        ar[1] = mfma16(ak, ld8(sp1 + k * 32), ar[1]);
        an[0] = mfma16(ak, asbf(wn[0][k]), an[0]);
        an[1] = mfma16(ak, asbf(wn[1][k]), an[1]);
        ak = ak1;
        if (k < 6) ak1 = ld8(hb + (k + 2) * 32);
      }

      // issue next-step x loads early (consumed after the pointwise)
      const int tn = (t + 1 < LX) ? t + 1 : 0;
      const float* xr = xbase + (size_t)tn * FF;
      const v4ff x0 = *(const v4ff*)(xr);
      const v4ff x1 = *(const v4ff*)(xr + 4);
      const v4ff x2 = *(const v4ff*)(xr + 32);
      const v4ff x3 = *(const v4ff*)(xr + 36);

      // x-part MFMAs: xa0/xa1 already in registers (pre-cvt'd last step)
#pragma unroll
      for (int j = 0; j < 2; ++j) {
        const int m = (wave + 8 * j) * 16 + col16;
        const u16* pwr = eWih + (size_t)m * FF + quad * 8;
        const u16* pwz = eWih + (size_t)(256 + m) * FF + quad * 8;
        const u16* pwn = eWih + (size_t)(512 + m) * FF + quad * 8;
        az[j] = mfma16(xa0, ld8(pwz), az[j]);
        az[j] = mfma16(xa1, ld8(pwz + 32), az[j]);
        ar[j] = mfma16(xa0, ld8(pwr), ar[j]);
        ar[j] = mfma16(xa1, ld8(pwr + 32), ar[j]);
        ai[j] = mfma16(xa0, ld8(pwn), ai[j]);
        ai[j] = mfma16(xa1, ld8(pwn + 32), ai[j]);
      }
      __builtin_amdgcn_s_setprio(0);

#pragma unroll
      for (int j = 0; j < 2; ++j) {
        const int cidx = (wave + 8 * j) * 16 + col16;
#pragma unroll
        for (int r = 0; r < 4; ++r) {
          const float zg = sigm(az[j][r]);
          const float rg = sigm(ar[j][r]);
          const float ng = tanh_(ai[j][r] + rg * an[j][r]);
          hreg[j][r] = (1.f - zg) * ng + zg * hreg[j][r];
          hls[(t + 1) & 1][(quad * 4 + r) * HSTR + cidx] = f2bf(hreg[j][r]);
        }
      }
      // pre-cvt x(t+1) fragments before the barrier
      xa0 = cvt2f(x0, x1);
      xa1 = cvt2f(x2, x3);
      __syncthreads();
    }
  }
  // h_enc in hls[LX & 1] == hls[0]  (LX even)

  // ================= decoder phase =================
  {
    for (int i = tid; i < 256 * 32; i += 512) {  // restage slab with dWhh r rows
      const int row = i >> 5, kb = (i & 31) << 3;
      *reinterpret_cast<v8bf*>(&slab[row * SSTR + kb]) = ld8(dWhh + row * HID + kb);
    }
    float hb0[2];
#pragma unroll
    for (int j = 0; j < 2; ++j) {
      const int c = wave + 8 * j;
      const int mr = c * 16 + col16, mz = 256 + mr, mn = 512 + mr;
#pragma unroll
      for (int k = 0; k < 8; ++k) {
        wz[j][k] = ldw(dWhh + (size_t)mz * HID + k * 32 + quad * 8); pin(wz[j][k]);
        wn[j][k] = ldw(dWhh + (size_t)mn * HID + k * 32 + quad * 8); pin(wn[j][k]);
      }
      bsr[j] = dbih[mr] + dbhh[mr];
      bsz[j] = dbih[mz] + dbhh[mz];
      bin_[j] = dbih[mn];
      bhn[j] = dbhh[mn];
      const int ml = wave * 16 + col16;
      hb0[j] = (j == 0) ? thb0[ml] : clb0[ml];
    }
    const bool w1th = (col16 < 2);
    const bool w1cl = (col16 >= 2 && col16 < FOUTC);
    const float b1v = w1th ? thb1[col16] : (w1cl ? clb1[col16 - 2] : 0.f);
    const u16* sp0 = slab + (wave * 16 + col16) * SSTR + quad * 8;
    const u16* sp1 = slab + ((wave + 8) * 16 + col16) * SSTR + quad * 8;

    const int srr = tid >> 5, scc = tid & 31;
    const size_t ybase = (size_t)(n0 + srr) * (LY + 1);
    {  // stage u_0 (src_t = 0)
      const float v = (scc < FT) ? yt[ybase * FT + scc] : pp[ybase * FOUTC + (scc - FT)];
      uls[0][srr * UST2 + scc] = f2bf(v);
    }
    __syncthreads();  // slab + u_0 visible (also last h write already fenced)

#pragma unroll 1
    for (int t = 0; t < LY; ++t) {
      float un = 0.f;
      if (t + 1 < LY)
        un = (scc < FT) ? yt[(ybase + t) * FT + scc]
                        : pp[(ybase + t) * FOUTC + (scc - FT)];
      const v8bf ua = ld8(uls[t & 1] + col16 * UST2 + quad * 8);
      const u16* hb = hls[0] + col16 * HSTR + quad * 8;  // h_t (single buffer)
      v8bf a[8];
#pragma unroll
      for (int k = 0; k < 8; ++k) a[k] = ld8(hb + k * 32);
      __syncthreads();  // barR: all hls[0]/uls reads done before rewrites

      // GEMM2 for step t-2 (wave 0): reads a1 buffer written in slot t-1.
      if (wave == 0 && t >= 2) {
        const u16* arow = ((t & 1) ? a1x : hls[1]) + col16 * HSTR + quad * 8;
        v4f acc = {b1v, b1v, b1v, b1v};
#pragma unroll
        for (int kt = 0; kt < 8; ++kt) {
          v8bf b;
#pragma unroll
          for (int j = 0; j < 8; ++j) b[j] = (__bf16)0.0f;
          if (kt < 4) { if (w1th) b = ld8(thW1 + col16 * 128 + kt * 32 + quad * 8); }
          else        { if (w1cl) b = ld8(clW1 + (col16 - 2) * 128 + (kt - 4) * 32 + quad * 8); }
          acc = mfma16(ld8(arow + kt * 32), b, acc);
        }
        if (col16 < FOUTC) {
#pragma unroll
          for (int r = 0; r < 4; ++r)
            outp[((size_t)(n0 + quad * 4 + r) * LY + (t - 2)) * FOUTC + col16] = acc[r];
        }
      }

      // gates (6 interleaved chains), bias-folded init
      v4f az[2], ar[2], an[2], ai[2];
#pragma unroll
      for (int j = 0; j < 2; ++j) {
        az[j] = (v4f){bsz[j], bsz[j], bsz[j], bsz[j]};
        ar[j] = (v4f){bsr[j], bsr[j], bsr[j], bsr[j]};
        an[j] = (v4f){bhn[j], bhn[j], bhn[j], bhn[j]};
        ai[j] = (v4f){bin_[j], bin_[j], bin_[j], bin_[j]};
      }
      __builtin_amdgcn_s_setprio(1);
#pragma unroll
      for (int k = 0; k < 8; ++k) {
        az[0] = mfma16(a[k], asbf(wz[0][k]), az[0]);
        az[1] = mfma16(a[k], asbf(wz[1][k]), az[1]);
        ar[0] = mfma16(a[k], ld8(sp0 + k * 32), ar[0]);
        ar[1] = mfma16(a[k], ld8(sp1 + k * 32), ar[1]);
        an[0] = mfma16(a[k], asbf(wn[0][k]), an[0]);
        an[1] = mfma16(a[k], asbf(wn[1][k]), an[1]);
      }
#pragma unroll
      for (int j = 0; j < 2; ++j) {
        const int m = (wave + 8 * j) * 16 + col16;
        az[j] = mfma16(ua, ld8(dWih + (size_t)(256 + m) * 32 + quad * 8), az[j]);
        ar[j] = mfma16(ua, ld8(dWih + (size_t)m * 32 + quad * 8), ar[j]);
        ai[j] = mfma16(ua, ld8(dWih + (size_t)(512 + m) * 32 + quad * 8), ai[j]);
      }
      __builtin_amdgcn_s_setprio(0);
#pragma unroll
      for (int j = 0; j < 2; ++j) {
        const int cidx = (wave + 8 * j) * 16 + col16;
#pragma unroll
        for (int r = 0; r < 4; ++r) {
          const float zg = sigm(az[j][r]);
          const float rg = sigm(ar[j][r]);
          const float ng = tanh_(ai[j][r] + rg * an[j][r]);
          hreg[j][r] = (1.f - zg) * ng + zg * hreg[j][r];
          hls[0][(quad * 4 + r) * HSTR + cidx] = f2bf(hreg[j][r]);
        }
      }

      // GEMM1 for step t-1: a[] == h_t == h2_{t-1} (zero extra LDS reads)
      if (t >= 1) {
        u16* a1w = ((t - 1) & 1) ? a1x : hls[1];
#pragma unroll
        for (int j = 0; j < 2; ++j) {
          const u16* W0 = (j == 0) ? thW0 : clW0;
          const u16* pw = W0 + (size_t)(wave * 16 + col16) * HID + quad * 8;
          v4f acc = {hb0[j], hb0[j], hb0[j], hb0[j]};
#pragma unroll
          for (int k = 0; k < 8; ++k) acc = mfma16(a[k], ld8(pw + k * 32), acc);
          const int c = wave + 8 * j;
#pragma unroll
          for (int r = 0; r < 4; ++r)
            a1w[(quad * 4 + r) * HSTR + c * 16 + col16] = f2bf(smelu_(acc[r]));
        }
      }
      if (t + 1 < LY) uls[(t + 1) & 1][srr * UST2 + scc] = f2bf(un);
      __syncthreads();  // barW: h_{t+1}, u_{t+1}, a1(t-1) visible
    }

    // ---- epilogue: GEMM1(LY-1), GEMM2(LY-2), then GEMM2(LY-1) ----
    {
      const u16* h2b = hls[0] + col16 * HSTR + quad * 8;  // h_LY = h2_{LY-1}
      v8bf ah2[8];
#pragma unroll
      for (int k = 0; k < 8; ++k) ah2[k] = ld8(h2b + k * 32);
      u16* a1w = ((LY - 1) & 1) ? a1x : hls[1];           // = a1x (LY-1 odd)
#pragma unroll
      for (int j = 0; j < 2; ++j) {
        const u16* W0 = (j == 0) ? thW0 : clW0;
        const u16* pw = W0 + (size_t)(wave * 16 + col16) * HID + quad * 8;
        v4f acc = {hb0[j], hb0[j], hb0[j], hb0[j]};
#pragma unroll
        for (int k = 0; k < 8; ++k) acc = mfma16(ah2[k], ld8(pw + k * 32), acc);
        const int c = wave + 8 * j;
#pragma unroll
        for (int r = 0; r < 4; ++r)
          a1w[(quad * 4 + r) * HSTR + c * 16 + col16] = f2bf(smelu_(acc[r]));
      }
      if (wave == 0) {  // GEMM2(LY-2): buffer written in slot LY-1, fenced by barW
        const u16* arow = (((LY - 2) & 1) ? a1x : hls[1]) + col16 * HSTR + quad * 8;
        v4f acc = {b1v, b1v, b1v, b1v};
#pragma unroll
        for (int kt = 0; kt < 8; ++kt) {
          v8bf b;
#pragma unroll
          for (int j = 0; j < 8; ++j) b[j] = (__bf16)0.0f;
          if (kt < 4) { if (w1th) b = ld8(thW1 + col16 * 128 + kt * 32 + quad * 8); }
          else        { if (w1cl) b = ld8(clW1 + (col16 - 2) * 128 + (kt - 4) * 32 + quad * 8); }
          acc = mfma16(ld8(arow + kt * 32), b, acc);
        }
        if (col16 < FOUTC) {
#pragma unroll
          for (int r = 0; r < 4; ++r)
            outp[((size_t)(n0 + quad * 4 + r) * LY + (LY - 2)) * FOUTC + col16] = acc[r];
        }
      }
      __syncthreads();
      if (wave == 0) {  // GEMM2(LY-1)
        const u16* arow = (((LY - 1) & 1) ? a1x : hls[1]) + col16 * HSTR + quad * 8;
        v4f acc = {b1v, b1v, b1v, b1v};
#pragma unroll
        for (int kt = 0; kt < 8; ++kt) {
          v8bf b;
#pragma unroll
          for (int j = 0; j < 8; ++j) b[j] = (__bf16)0.0f;
          if (kt < 4) { if (w1th) b = ld8(thW1 + col16 * 128 + kt * 32 + quad * 8); }
          else        { if (w1cl) b = ld8(clW1 + (col16 - 2) * 128 + (kt - 4) * 32 + quad * 8); }
          acc = mfma16(ld8(arow + kt * 32), b, acc);
        }
        if (col16 < FOUTC) {
#pragma unroll
          for (int r = 0; r < 4; ++r)
            outp[((size_t)(n0 + quad * 4 + r) * LY + (LY - 1)) * FOUTC + col16] = acc[r];
        }
      }
    }
  }
}

extern "C" void kernel_launch(void* const* d_in, const int* in_sizes, int n_in,
                              void* d_out, int out_size, void* d_ws, size_t ws_size,
                              hipStream_t stream) {
  (void)in_sizes; (void)n_in; (void)ws_size; (void)out_size;
  const float* xf   = (const float*)d_in[0];
  // d_in[1] = x : unused by forward
  const float* yt   = (const float*)d_in[2];
  const float* pp   = (const float*)d_in[3];
  const float* eWih = (const float*)d_in[4];
  const float* eWhh = (const float*)d_in[5];
  const float* ebih = (const float*)d_in[6];
  const float* ebhh = (const float*)d_in[7];
  const float* dWih = (const float*)d_in[8];
  const float* dWhh = (const float*)d_in[9];
  const float* dbih = (const float*)d_in[10];
  const float* dbhh = (const float*)d_in[11];
  const float* thW0 = (const float*)d_in[12];
  const float* thb0 = (const float*)d_in[13];
  const float* thW1 = (const float*)d_in[14];
  const float* thb1 = (const float*)d_in[15];
  const float* clW0 = (const float*)d_in[16];
  const float* clb0 = (const float*)d_in[17];
  const float* clW1 = (const float*)d_in[18];
  const float* clb1 = (const float*)d_in[19];
  float* outp = (float*)d_out;
  u16* ws = (u16*)d_ws;  // needs W_TOTAL*2 ~= 1.04 MB of scratch

  cvt_weights<<<dim3((W_TOTAL + 255) / 256), dim3(256), 0, stream>>>(
      eWih, eWhh, dWih, dWhh, thW0, thW1, clW0, clW1, ws);
  encdec_kernel<<<dim3(128), dim3(512), 0, stream>>>(
      xf, yt, pp, ebih, ebhh, dbih, dbhh, thb0, thb1, clb0, clb1, ws, outp);
}